// Round 9
// baseline (860.387 us; speedup 1.0000x reference)
//
#include <hip/hip_runtime.h>

typedef unsigned short u16;
typedef __attribute__((ext_vector_type(8))) short short8v;
typedef __attribute__((ext_vector_type(4))) float float4v;

__device__ __forceinline__ float bf2f(u16 u) {
  union { unsigned int i; float f; } v; v.i = ((unsigned int)u) << 16; return v.f;
}
__device__ __forceinline__ u16 f2bf(float f) {
  union { unsigned int i; float f; } v; v.f = f;
  unsigned int r = v.i + 0x7fffu + ((v.i >> 16) & 1u);
  return (u16)(r >> 16);
}
__device__ __forceinline__ float4v mfma_bf16(short8v a, short8v b, float4v c) {
  return __builtin_amdgcn_mfma_f32_16x16x32_bf16(a, b, c, 0, 0, 0);
}

// ---------------------------------------------------------------------------
// prep: Bt[j][c] (1536x256 bf16) = W[j][c] (j<768) / W[j-768][256+c]
//       W2t[j][k] (768x64 bf16)  = W[j][512+k]        (W is fp32 768x576)
// ---------------------------------------------------------------------------
__global__ __launch_bounds__(256) void prep_kernel(const float* __restrict__ W,
                                                   u16* __restrict__ Bt,
                                                   u16* __restrict__ W2t) {
  int j = blockIdx.x;      // 0..767
  int c = threadIdx.x;     // 0..255
  const float* wr = W + (size_t)j * 576;
  Bt[(size_t)j * 256 + c]         = f2bf(wr[c]);
  Bt[(size_t)(768 + j) * 256 + c] = f2bf(wr[256 + c]);
  if (c < 64) W2t[(size_t)j * 64 + c] = f2bf(wr[512 + c]);
}

// ---------------------------------------------------------------------------
// gemm: Y (M x 1536 bf16) = x (M x 256 fp32) @ Bt^T   (Bt is 1536 x 256 bf16)
// 128x128 tile, 4 waves, each wave 64x64 (4x4 frags of 16x16x32 bf16).
// 1-D grid of 3756 = 313 row-tiles x 12 col-tiles, XCD-chunked bijective
// swizzle (8 XCDs): within a chunk consecutive blocks are the 12 col-tiles
// of ONE row-tile -> the A row-tile is fetched once into that XCD's L2 and
// re-hit 11x (x crosses the fabric ~once, 41MB, instead of 12x ~490MB).
// Y written with non-temporal stores (write-once stream; keeps L2/L3 clean
// for A reuse and the triplet's Y gathers).
// ---------------------------------------------------------------------------
#define G1_NWG   3756   // 313 * 12
#define G1_NXCD  8
__global__ __launch_bounds__(256) void gemm_kernel(const float* __restrict__ A,
                                                   const u16* __restrict__ Bt,
                                                   u16* __restrict__ Y, int M) {
  __shared__ __align__(16) u16 As[128][72];
  __shared__ __align__(16) u16 Bs[128][72];
  int tid = threadIdx.x;

  // bijective XCD-chunk swizzle (m204): chunk q/r split
  int bid = blockIdx.x;
  const int q = G1_NWG / G1_NXCD;          // 469
  const int r = G1_NWG % G1_NXCD;          // 4
  int xcd = bid % G1_NXCD;
  int idx = bid / G1_NXCD;
  int wgid = (xcd < r ? xcd * (q + 1) : r * (q + 1) + (xcd - r) * q) + idx;
  int rt = wgid / 12;                      // row-tile 0..312
  int ct = wgid % 12;                      // col-tile 0..11 (fastest in chunk)
  int row0 = rt * 128, col0 = ct * 128;

  int w = tid >> 6, l = tid & 63;
  int wr = w >> 1, wc = w & 1;
  int lr = l & 15, lq = l >> 4;

  float4v acc[4][4];
#pragma unroll
  for (int mi = 0; mi < 4; mi++)
#pragma unroll
    for (int ni = 0; ni < 4; ni++) acc[mi][ni] = (float4v)0.f;

  for (int k0 = 0; k0 < 256; k0 += 64) {
#pragma unroll
    for (int i = 0; i < 4; i++) {
      int chunk = tid + i * 256;       // 0..1023
      int rr = chunk >> 3;             // 0..127
      int kc = (chunk & 7) * 8;        // 0..56
      int gr = row0 + rr;
      short8v av = (short8v)0;
      if (gr < M) {
        float4 f0 = *(const float4*)(A + (size_t)gr * 256 + k0 + kc);
        float4 f1 = *(const float4*)(A + (size_t)gr * 256 + k0 + kc + 4);
        av[0] = (short)f2bf(f0.x); av[1] = (short)f2bf(f0.y);
        av[2] = (short)f2bf(f0.z); av[3] = (short)f2bf(f0.w);
        av[4] = (short)f2bf(f1.x); av[5] = (short)f2bf(f1.y);
        av[6] = (short)f2bf(f1.z); av[7] = (short)f2bf(f1.w);
      }
      *(short8v*)&As[rr][kc] = av;
      short8v bv = *(const short8v*)(Bt + (size_t)(col0 + rr) * 256 + k0 + kc);
      *(short8v*)&Bs[rr][kc] = bv;
    }
    __syncthreads();
#pragma unroll
    for (int s = 0; s < 2; s++) {
      int kb = s * 32 + lq * 8;
      short8v af[4], bf[4];
#pragma unroll
      for (int mi = 0; mi < 4; mi++)
        af[mi] = *(const short8v*)&As[wr * 64 + mi * 16 + lr][kb];
#pragma unroll
      for (int ni = 0; ni < 4; ni++)
        bf[ni] = *(const short8v*)&Bs[wc * 64 + ni * 16 + lr][kb];
#pragma unroll
      for (int mi = 0; mi < 4; mi++)
#pragma unroll
        for (int ni = 0; ni < 4; ni++)
          acc[mi][ni] = mfma_bf16(af[mi], bf[ni], acc[mi][ni]);
    }
    __syncthreads();
  }
#pragma unroll
  for (int mi = 0; mi < 4; mi++)
#pragma unroll
    for (int ni = 0; ni < 4; ni++) {
      int rbase = row0 + wr * 64 + mi * 16 + lq * 4;
      int c = col0 + wc * 64 + ni * 16 + lr;
#pragma unroll
      for (int j = 0; j < 4; j++) {
        int rI = rbase + j;
        if (rI < M)
          __builtin_nontemporal_store(f2bf(acc[mi][ni][j]),
                                      &Y[(size_t)rI * 1536 + c]);
      }
    }
}

// ---------------------------------------------------------------------------
// triplet: one 256-thread block (4 waves) per node n. Round-6 structure
// (best measured: 640us): D[t][chan] via mfma(ang, w2), scalar u16 Y gathers
// (4 distinct rows / instruction), 48 epilogue tiles split 12-per-wave,
// 25KB LDS -> 6 blocks/CU -> ~68% occupancy. nt hints on write-once traffic.
// ---------------------------------------------------------------------------
__global__ __launch_bounds__(256) void triplet_kernel(
    const float* __restrict__ x, const float* __restrict__ pos,
    const int* __restrict__ anchor, const int* __restrict__ corner,
    const float* __restrict__ bias, const u16* __restrict__ Y,
    const u16* __restrict__ W2t, float* __restrict__ out, int N) {
  __shared__ float s_cos[16];
  __shared__ float s_div[32];
  __shared__ int s_i0[16], s_i1[16];
  __shared__ __align__(16) u16 s_qkv[16][776];   // rows: triplet, cols: 768 ch (+8 pad)

  int n = blockIdx.x;
  if (n >= N) return;
  int tid = threadIdx.x;
  int w = tid >> 6;            // wave 0..3
  int l = tid & 63;
  int lr = l & 15, lq = l >> 4, kg = lq * 8;
  int a = anchor[n];

  if (tid < 32) s_div[tid] = __expf(-0.28782313662425572f * (float)tid);
  if (tid < 16) {
    int t = tid;
    int2 ci = ((const int2*)corner)[n * 16 + t];
    float ax = pos[(size_t)a * 3], ay = pos[(size_t)a * 3 + 1];
    float v0x = pos[(size_t)ci.x * 3]     - ax;
    float v0y = pos[(size_t)ci.x * 3 + 1] - ay;
    float v1x = pos[(size_t)ci.y * 3]     - ax;
    float v1y = pos[(size_t)ci.y * 3 + 1] - ay;
    float dot = v0x * v1x + v0y * v1y;
    float n0 = sqrtf(v0x * v0x + v0y * v0y);
    float n1 = sqrtf(v1x * v1x + v1y * v1y);
    s_cos[t] = dot / (n0 * n1 + 1e-6f);
    float sinz = v0x * v1y - v0y * v1x;
    bool sw = sinz < 0.f;
    s_i0[t] = sw ? ci.y : ci.x;
    s_i1[t] = sw ? ci.x : ci.y;
    // triplet_false_masks is provably always false -> 0.0f (nt store)
    __builtin_nontemporal_store(0.0f, &out[(size_t)N * 512 + (size_t)n * 16 + t]);
  }
  // copy x row -> out[n][0:256]  (fp32 passthrough, stream-once: nt both ways)
  if (tid < 64) {
    const float4v* src = (const float4v*)(x + (size_t)n * 256);
    float4v* dst = (float4v*)(out + (size_t)n * 512);
    float4v v = __builtin_nontemporal_load(src + tid);
    __builtin_nontemporal_store(v, dst + tid);
  }
  __syncthreads();

  // angle-embedding A fragments (row = triplet t = lr, k-chunk = lq*8).
  // Same values in every wave; sin/cos pairs of the same angle, div_term
  // from the LDS table.
  float cosv = s_cos[lr];
  short8v a0, a1;
#pragma unroll
  for (int jj = 0; jj < 4; jj++) {
    int kh = (kg >> 1) + jj;           // k>>1 for the pair in [0,16)
    float om0 = cosv * s_div[kh];
    a0[2 * jj]     = (short)f2bf(__sinf(om0));
    a0[2 * jj + 1] = (short)f2bf(__cosf(om0));
    float om1 = cosv * s_div[16 + kh];
    a1[2 * jj]     = (short)f2bf(__sinf(om1));
    a1[2 * jj + 1] = (short)f2bf(__cosf(om1));
  }
  int i0r[4], i1r[4];
#pragma unroll
  for (int j = 0; j < 4; j++) {
    int t = lq * 4 + j;
    i0r[j] = s_i0[t];
    i1r[j] = s_i1[t];
  }

  // T = ang @ W2t, fused epilogue: + bias + Y0[i0] + Y1[i1] -> qkv LDS.
  // Wave w owns channel tiles [w*12, w*12+12). Scalar u16 gathers:
  // 4 distinct Y rows per instruction, 32B contiguous per row.
  for (int u = 0; u < 12; u++) {
    int nt = w * 12 + u;
    int col = nt * 16 + lr;
    short8v b0 = *(const short8v*)(W2t + (size_t)col * 64 + kg);
    short8v b1 = *(const short8v*)(W2t + (size_t)col * 64 + 32 + kg);
    float4v acc = (float4v)0.f;
    acc = mfma_bf16(a0, b0, acc);
    acc = mfma_bf16(a1, b1, acc);
    float bs = bias[col];
#pragma unroll
    for (int j = 0; j < 4; j++) {
      float v = acc[j] + bs + bf2f(Y[(size_t)i0r[j] * 1536 + col]) +
                bf2f(Y[(size_t)i1r[j] * 1536 + 768 + col]);
      s_qkv[lq * 4 + j][col] = f2bf(v);
    }
  }
  __syncthreads();

  // scores = Q @ K^T (redundantly per wave; both frags contiguous in LDS)
  float4v sa = (float4v)0.f;
#pragma unroll
  for (int cs = 0; cs < 8; cs++) {
    short8v qf = *(const short8v*)&s_qkv[lr][cs * 32 + kg];
    short8v kf = *(const short8v*)&s_qkv[lr][256 + cs * 32 + kg];
    sa = mfma_bf16(qf, kf, sa);
  }
  // softmax per row q=(lq*4+j) over 16 lanes (kk=lr), then column-mean -> w
  float wsum = 0.f;
#pragma unroll
  for (int j = 0; j < 4; j++) {
    float s = sa[j] * 0.0625f;   // / sqrt(256)
    float m = s;
    m = fmaxf(m, __shfl_xor(m, 1));
    m = fmaxf(m, __shfl_xor(m, 2));
    m = fmaxf(m, __shfl_xor(m, 4));
    m = fmaxf(m, __shfl_xor(m, 8));
    float e = __expf(s - m);
    float sm = e;
    sm += __shfl_xor(sm, 1);
    sm += __shfl_xor(sm, 2);
    sm += __shfl_xor(sm, 4);
    sm += __shfl_xor(sm, 8);
    wsum += e / sm;
  }
  wsum += __shfl_xor(wsum, 16);
  wsum += __shfl_xor(wsum, 32);
  wsum *= 0.0625f;               // w[kk = l&15], replicated across lane groups

  // out[a][256 + c], c = w*64 + l : each wave covers 64 output channels
  int c = (w << 6) + l;
  float o = 0.f;
#pragma unroll
  for (int kk = 0; kk < 16; kk++) {
    float wk = __shfl(wsum, kk);
    o += wk * bf2f(s_qkv[kk][512 + c]);
  }
  __builtin_nontemporal_store(o, &out[(size_t)a * 512 + 256 + c]);
}

// ---------------------------------------------------------------------------
extern "C" void kernel_launch(void* const* d_in, const int* in_sizes, int n_in,
                              void* d_out, int out_size, void* d_ws, size_t ws_size,
                              hipStream_t stream) {
  const float* x    = (const float*)d_in[0];
  const float* pos  = (const float*)d_in[1];
  const int* anchor = (const int*)d_in[2];
  const int* corner = (const int*)d_in[3];
  // d_in[4] = corner_masks: all-ones by construction, unused
  const float* W    = (const float*)d_in[5];
  const float* bias = (const float*)d_in[6];
  float* out = (float*)d_out;
  int N = in_sizes[2];   // 40000

  char* wsb = (char*)d_ws;
  u16* Bt  = (u16*)wsb;                          // 1536*256*2 = 786432 B
  u16* W2t = (u16*)(wsb + 786432);               // 768*64*2   =  98304 B
  u16* Y   = (u16*)(wsb + 786432 + 98304);       // N*1536*2   = 122.88 MB

  prep_kernel<<<768, 256, 0, stream>>>(W, Bt, W2t);
  gemm_kernel<<<G1_NWG, 256, 0, stream>>>(x, Bt, Y, N);
  triplet_kernel<<<N, 256, 0, stream>>>(x, pos, anchor, corner, bias, Y, W2t, out, N);
}

// Round 10
// 804.297 us; speedup vs baseline: 1.0697x; 1.0697x over previous
//
#include <hip/hip_runtime.h>

typedef unsigned short u16;
typedef __attribute__((ext_vector_type(8))) short short8v;
typedef __attribute__((ext_vector_type(4))) float float4v;

__device__ __forceinline__ float bf2f(u16 u) {
  union { unsigned int i; float f; } v; v.i = ((unsigned int)u) << 16; return v.f;
}
__device__ __forceinline__ u16 f2bf(float f) {
  union { unsigned int i; float f; } v; v.f = f;
  unsigned int r = v.i + 0x7fffu + ((v.i >> 16) & 1u);
  return (u16)(r >> 16);
}
__device__ __forceinline__ float4v mfma_bf16(short8v a, short8v b, float4v c) {
  return __builtin_amdgcn_mfma_f32_16x16x32_bf16(a, b, c, 0, 0, 0);
}

// ---------------------------------------------------------------------------
// prep: Bt[j][c] (1536x256 bf16) = W[j][c] (j<768) / W[j-768][256+c]
//       W2t[j][k] (768x64 bf16)  = W[j][512+k]        (W is fp32 768x576)
// ---------------------------------------------------------------------------
__global__ __launch_bounds__(256) void prep_kernel(const float* __restrict__ W,
                                                   u16* __restrict__ Bt,
                                                   u16* __restrict__ W2t) {
  int j = blockIdx.x;      // 0..767
  int c = threadIdx.x;     // 0..255
  const float* wr = W + (size_t)j * 576;
  Bt[(size_t)j * 256 + c]         = f2bf(wr[c]);
  Bt[(size_t)(768 + j) * 256 + c] = f2bf(wr[256 + c]);
  if (c < 64) W2t[(size_t)j * 64 + c] = f2bf(wr[512 + c]);
}

// ---------------------------------------------------------------------------
// gemm: Y (M x 1536 bf16) = x (M x 256 fp32) @ Bt^T   (Bt is 1536 x 256 bf16)
// 128x128 tile, 4 waves, each wave 64x64 (4x4 frags of 16x16x32 bf16)
// Plain 2-D grid, plain stores: r8 (row-persistent) and r9 (XCD swizzle +
// nt stores) both regressed vs this shape -- keep it simple.
// ---------------------------------------------------------------------------
__global__ __launch_bounds__(256) void gemm_kernel(const float* __restrict__ A,
                                                   const u16* __restrict__ Bt,
                                                   u16* __restrict__ Y, int M) {
  __shared__ __align__(16) u16 As[128][72];
  __shared__ __align__(16) u16 Bs[128][72];
  int tid = threadIdx.x;
  int row0 = blockIdx.x * 128, col0 = blockIdx.y * 128;
  int w = tid >> 6, l = tid & 63;
  int wr = w >> 1, wc = w & 1;
  int lr = l & 15, lq = l >> 4;

  float4v acc[4][4];
#pragma unroll
  for (int mi = 0; mi < 4; mi++)
#pragma unroll
    for (int ni = 0; ni < 4; ni++) acc[mi][ni] = (float4v)0.f;

  for (int k0 = 0; k0 < 256; k0 += 64) {
#pragma unroll
    for (int i = 0; i < 4; i++) {
      int chunk = tid + i * 256;       // 0..1023
      int r = chunk >> 3;              // 0..127
      int kc = (chunk & 7) * 8;        // 0..56
      int gr = row0 + r;
      short8v av = (short8v)0;
      if (gr < M) {
        float4 f0 = *(const float4*)(A + (size_t)gr * 256 + k0 + kc);
        float4 f1 = *(const float4*)(A + (size_t)gr * 256 + k0 + kc + 4);
        av[0] = (short)f2bf(f0.x); av[1] = (short)f2bf(f0.y);
        av[2] = (short)f2bf(f0.z); av[3] = (short)f2bf(f0.w);
        av[4] = (short)f2bf(f1.x); av[5] = (short)f2bf(f1.y);
        av[6] = (short)f2bf(f1.z); av[7] = (short)f2bf(f1.w);
      }
      *(short8v*)&As[r][kc] = av;
      short8v bv = *(const short8v*)(Bt + (size_t)(col0 + r) * 256 + k0 + kc);
      *(short8v*)&Bs[r][kc] = bv;
    }
    __syncthreads();
#pragma unroll
    for (int s = 0; s < 2; s++) {
      int kb = s * 32 + lq * 8;
      short8v af[4], bf[4];
#pragma unroll
      for (int mi = 0; mi < 4; mi++)
        af[mi] = *(const short8v*)&As[wr * 64 + mi * 16 + lr][kb];
#pragma unroll
      for (int ni = 0; ni < 4; ni++)
        bf[ni] = *(const short8v*)&Bs[wc * 64 + ni * 16 + lr][kb];
#pragma unroll
      for (int mi = 0; mi < 4; mi++)
#pragma unroll
        for (int ni = 0; ni < 4; ni++)
          acc[mi][ni] = mfma_bf16(af[mi], bf[ni], acc[mi][ni]);
    }
    __syncthreads();
  }
#pragma unroll
  for (int mi = 0; mi < 4; mi++)
#pragma unroll
    for (int ni = 0; ni < 4; ni++) {
      int rbase = row0 + wr * 64 + mi * 16 + lq * 4;
      int c = col0 + wc * 64 + ni * 16 + lr;
#pragma unroll
      for (int j = 0; j < 4; j++) {
        int r = rbase + j;
        if (r < M) Y[(size_t)r * 1536 + c] = f2bf(acc[mi][ni][j]);
      }
    }
}

// ---------------------------------------------------------------------------
// triplet: one 256-thread block (4 waves) per node n. Round-6 structure
// (best measured: 640us): D[t][chan] via mfma(ang, w2), scalar u16 Y gathers
// (4 distinct rows / instruction), 48 epilogue tiles split 12-per-wave,
// 25KB LDS -> 6 blocks/CU -> ~68% occupancy. nt hints on write-once traffic.
// Pinned at ~92% of the scattered-line service floor (~1.0GB HBM-miss @
// ~1.7 TB/s): request shape, occupancy, nt hints, V-factoring all measured
// null or negative (rounds 0-7).
// ---------------------------------------------------------------------------
__global__ __launch_bounds__(256) void triplet_kernel(
    const float* __restrict__ x, const float* __restrict__ pos,
    const int* __restrict__ anchor, const int* __restrict__ corner,
    const float* __restrict__ bias, const u16* __restrict__ Y,
    const u16* __restrict__ W2t, float* __restrict__ out, int N) {
  __shared__ float s_cos[16];
  __shared__ float s_div[32];
  __shared__ int s_i0[16], s_i1[16];
  __shared__ __align__(16) u16 s_qkv[16][776];   // rows: triplet, cols: 768 ch (+8 pad)

  int n = blockIdx.x;
  if (n >= N) return;
  int tid = threadIdx.x;
  int w = tid >> 6;            // wave 0..3
  int l = tid & 63;
  int lr = l & 15, lq = l >> 4, kg = lq * 8;
  int a = anchor[n];

  if (tid < 32) s_div[tid] = __expf(-0.28782313662425572f * (float)tid);
  if (tid < 16) {
    int t = tid;
    int2 ci = ((const int2*)corner)[n * 16 + t];
    float ax = pos[(size_t)a * 3], ay = pos[(size_t)a * 3 + 1];
    float v0x = pos[(size_t)ci.x * 3]     - ax;
    float v0y = pos[(size_t)ci.x * 3 + 1] - ay;
    float v1x = pos[(size_t)ci.y * 3]     - ax;
    float v1y = pos[(size_t)ci.y * 3 + 1] - ay;
    float dot = v0x * v1x + v0y * v1y;
    float n0 = sqrtf(v0x * v0x + v0y * v0y);
    float n1 = sqrtf(v1x * v1x + v1y * v1y);
    s_cos[t] = dot / (n0 * n1 + 1e-6f);
    float sinz = v0x * v1y - v0y * v1x;
    bool sw = sinz < 0.f;
    s_i0[t] = sw ? ci.y : ci.x;
    s_i1[t] = sw ? ci.x : ci.y;
    // triplet_false_masks is provably always false -> 0.0f (nt store)
    __builtin_nontemporal_store(0.0f, &out[(size_t)N * 512 + (size_t)n * 16 + t]);
  }
  // copy x row -> out[n][0:256]  (fp32 passthrough, stream-once: nt both ways)
  if (tid < 64) {
    const float4v* src = (const float4v*)(x + (size_t)n * 256);
    float4v* dst = (float4v*)(out + (size_t)n * 512);
    float4v v = __builtin_nontemporal_load(src + tid);
    __builtin_nontemporal_store(v, dst + tid);
  }
  __syncthreads();

  // angle-embedding A fragments (row = triplet t = lr, k-chunk = lq*8).
  // Same values in every wave; sin/cos pairs of the same angle, div_term
  // from the LDS table.
  float cosv = s_cos[lr];
  short8v a0, a1;
#pragma unroll
  for (int jj = 0; jj < 4; jj++) {
    int kh = (kg >> 1) + jj;           // k>>1 for the pair in [0,16)
    float om0 = cosv * s_div[kh];
    a0[2 * jj]     = (short)f2bf(__sinf(om0));
    a0[2 * jj + 1] = (short)f2bf(__cosf(om0));
    float om1 = cosv * s_div[16 + kh];
    a1[2 * jj]     = (short)f2bf(__sinf(om1));
    a1[2 * jj + 1] = (short)f2bf(__cosf(om1));
  }
  int i0r[4], i1r[4];
#pragma unroll
  for (int j = 0; j < 4; j++) {
    int t = lq * 4 + j;
    i0r[j] = s_i0[t];
    i1r[j] = s_i1[t];
  }

  // T = ang @ W2t, fused epilogue: + bias + Y0[i0] + Y1[i1] -> qkv LDS.
  // Wave w owns channel tiles [w*12, w*12+12). Scalar u16 gathers:
  // 4 distinct Y rows per instruction, 32B contiguous per row.
  for (int u = 0; u < 12; u++) {
    int nt = w * 12 + u;
    int col = nt * 16 + lr;
    short8v b0 = *(const short8v*)(W2t + (size_t)col * 64 + kg);
    short8v b1 = *(const short8v*)(W2t + (size_t)col * 64 + 32 + kg);
    float4v acc = (float4v)0.f;
    acc = mfma_bf16(a0, b0, acc);
    acc = mfma_bf16(a1, b1, acc);
    float bs = bias[col];
#pragma unroll
    for (int j = 0; j < 4; j++) {
      float v = acc[j] + bs + bf2f(Y[(size_t)i0r[j] * 1536 + col]) +
                bf2f(Y[(size_t)i1r[j] * 1536 + 768 + col]);
      s_qkv[lq * 4 + j][col] = f2bf(v);
    }
  }
  __syncthreads();

  // scores = Q @ K^T (redundantly per wave; both frags contiguous in LDS)
  float4v sa = (float4v)0.f;
#pragma unroll
  for (int cs = 0; cs < 8; cs++) {
    short8v qf = *(const short8v*)&s_qkv[lr][cs * 32 + kg];
    short8v kf = *(const short8v*)&s_qkv[lr][256 + cs * 32 + kg];
    sa = mfma_bf16(qf, kf, sa);
  }
  // softmax per row q=(lq*4+j) over 16 lanes (kk=lr), then column-mean -> w
  float wsum = 0.f;
#pragma unroll
  for (int j = 0; j < 4; j++) {
    float s = sa[j] * 0.0625f;   // / sqrt(256)
    float m = s;
    m = fmaxf(m, __shfl_xor(m, 1));
    m = fmaxf(m, __shfl_xor(m, 2));
    m = fmaxf(m, __shfl_xor(m, 4));
    m = fmaxf(m, __shfl_xor(m, 8));
    float e = __expf(s - m);
    float sm = e;
    sm += __shfl_xor(sm, 1);
    sm += __shfl_xor(sm, 2);
    sm += __shfl_xor(sm, 4);
    sm += __shfl_xor(sm, 8);
    wsum += e / sm;
  }
  wsum += __shfl_xor(wsum, 16);
  wsum += __shfl_xor(wsum, 32);
  wsum *= 0.0625f;               // w[kk = l&15], replicated across lane groups

  // out[a][256 + c], c = w*64 + l : each wave covers 64 output channels
  int c = (w << 6) + l;
  float o = 0.f;
#pragma unroll
  for (int kk = 0; kk < 16; kk++) {
    float wk = __shfl(wsum, kk);
    o += wk * bf2f(s_qkv[kk][512 + c]);
  }
  __builtin_nontemporal_store(o, &out[(size_t)a * 512 + 256 + c]);
}

// ---------------------------------------------------------------------------
extern "C" void kernel_launch(void* const* d_in, const int* in_sizes, int n_in,
                              void* d_out, int out_size, void* d_ws, size_t ws_size,
                              hipStream_t stream) {
  const float* x    = (const float*)d_in[0];
  const float* pos  = (const float*)d_in[1];
  const int* anchor = (const int*)d_in[2];
  const int* corner = (const int*)d_in[3];
  // d_in[4] = corner_masks: all-ones by construction, unused
  const float* W    = (const float*)d_in[5];
  const float* bias = (const float*)d_in[6];
  float* out = (float*)d_out;
  int N = in_sizes[2];   // 40000

  char* wsb = (char*)d_ws;
  u16* Bt  = (u16*)wsb;                          // 1536*256*2 = 786432 B
  u16* W2t = (u16*)(wsb + 786432);               // 768*64*2   =  98304 B
  u16* Y   = (u16*)(wsb + 786432 + 98304);       // N*1536*2   = 122.88 MB

  prep_kernel<<<768, 256, 0, stream>>>(W, Bt, W2t);
  gemm_kernel<<<dim3((N + 127) / 128, 12), 256, 0, stream>>>(x, Bt, Y, N);
  triplet_kernel<<<N, 256, 0, stream>>>(x, pos, anchor, corner, bias, Y, W2t, out, N);
}